// Round 1
// baseline (84.406 us; speedup 1.0000x reference)
//
#include <hip/hip_runtime.h>

// YibeiVessels: fused per-voxel LUT gather + onehot channel synthesis.
// out layout (flat f32): [ out_vol (V) | ch0 (V) | ch1 (V) | ch2 (V) ], V = 256^3.

#define N_IDS 257
#define VOL (256 * 256 * 256)

__global__ __launch_bounds__(256) void YibeiVessels_74156905333425_kernel(
    const int* __restrict__ labels,
    const float* __restrict__ intensities,
    const int* __restrict__ class_bits,
    const float* __restrict__ parenchyma,
    float* __restrict__ out)
{
    // Pre-fused LUTs in LDS (2 KB total):
    //   s_scale[id] : scaling factor (1.0 for background id 0)
    //   s_c1[id]    : 1.0 iff vessel (id>0) and class_bits[id]==0
    // Channels: ch0 = 1 - is_vessel; ch2 = is_vessel - ch1.
    __shared__ float s_scale[N_IDS];
    __shared__ float s_c1[N_IDS];

    const int tid = threadIdx.x;
    for (int i = tid; i < N_IDS; i += 256) {
        const float inten = intensities[i];
        const int cb = class_bits[i];
        const bool vessel = (i > 0);
        s_scale[i] = vessel ? inten : 1.0f;
        s_c1[i] = (vessel && cb == 0) ? 1.0f : 0.0f;
    }
    __syncthreads();

    const int nquads = VOL / 4;                       // 4,194,304 float4 groups
    const int stride = gridDim.x * blockDim.x;

    const int4*   lab4 = reinterpret_cast<const int4*>(labels);
    const float4* par4 = reinterpret_cast<const float4*>(parenchyma);
    float4* vol4 = reinterpret_cast<float4*>(out);
    float4* c04  = reinterpret_cast<float4*>(out + (size_t)VOL);
    float4* c14  = reinterpret_cast<float4*>(out + 2 * (size_t)VOL);
    float4* c24  = reinterpret_cast<float4*>(out + 3 * (size_t)VOL);

    for (int q = blockIdx.x * blockDim.x + tid; q < nquads; q += stride) {
        const int4 lab = lab4[q];
        const float4 par = par4[q];

        float4 vol, c0, c1, c2;

        {
            const int l = lab.x;
            const float vf = (l > 0) ? 1.0f : 0.0f;
            vol.x = par.x * s_scale[l];
            c1.x = s_c1[l];
            c0.x = 1.0f - vf;
            c2.x = vf - c1.x;
        }
        {
            const int l = lab.y;
            const float vf = (l > 0) ? 1.0f : 0.0f;
            vol.y = par.y * s_scale[l];
            c1.y = s_c1[l];
            c0.y = 1.0f - vf;
            c2.y = vf - c1.y;
        }
        {
            const int l = lab.z;
            const float vf = (l > 0) ? 1.0f : 0.0f;
            vol.z = par.z * s_scale[l];
            c1.z = s_c1[l];
            c0.z = 1.0f - vf;
            c2.z = vf - c1.z;
        }
        {
            const int l = lab.w;
            const float vf = (l > 0) ? 1.0f : 0.0f;
            vol.w = par.w * s_scale[l];
            c1.w = s_c1[l];
            c0.w = 1.0f - vf;
            c2.w = vf - c1.w;
        }

        vol4[q] = vol;
        c04[q]  = c0;
        c14[q]  = c1;
        c24[q]  = c2;
    }
}

extern "C" void kernel_launch(void* const* d_in, const int* in_sizes, int n_in,
                              void* d_out, int out_size, void* d_ws, size_t ws_size,
                              hipStream_t stream) {
    const int*   labels      = (const int*)d_in[0];
    const float* intensities = (const float*)d_in[1];
    const int*   class_bits  = (const int*)d_in[2];
    const float* parenchyma  = (const float*)d_in[3];
    float* out = (float*)d_out;

    const int blocks = 2048;   // 256 CUs x 8 blocks; grid-stride covers 4.19M quads
    YibeiVessels_74156905333425_kernel<<<blocks, 256, 0, stream>>>(
        labels, intensities, class_bits, parenchyma, out);
}

// Round 3
// 78.259 us; speedup vs baseline: 1.0786x; 1.0786x over previous
//
#include <hip/hip_runtime.h>

// YibeiVessels: fused per-voxel LUT gather + onehot channel synthesis.
// out layout (flat f32): [ out_vol (V) | ch0 (V) | ch1 (V) | ch2 (V) ], V = 256^3.
//
// R2: nontemporal loads/stores via clang ext_vector types (HIP_vector_type
// float4/int4 are structs -> rejected by __builtin_nontemporal_*).

#define N_IDS 257
#define VOL (256 * 256 * 256)

typedef float f32x4 __attribute__((ext_vector_type(4)));
typedef int   i32x4 __attribute__((ext_vector_type(4)));

__global__ __launch_bounds__(256) void YibeiVessels_74156905333425_kernel(
    const int* __restrict__ labels,
    const float* __restrict__ intensities,
    const int* __restrict__ class_bits,
    const float* __restrict__ parenchyma,
    float* __restrict__ out)
{
    // Pre-fused LUTs in LDS (2 KB total):
    //   s_scale[id] : scaling factor (1.0 for background id 0)
    //   s_c1[id]    : 1.0 iff vessel (id>0) and class_bits[id]==0
    // Channels: ch0 = 1 - is_vessel; ch2 = is_vessel - ch1.
    __shared__ float s_scale[N_IDS];
    __shared__ float s_c1[N_IDS];

    const int tid = threadIdx.x;
    for (int i = tid; i < N_IDS; i += 256) {
        const float inten = intensities[i];
        const int cb = class_bits[i];
        const bool vessel = (i > 0);
        s_scale[i] = vessel ? inten : 1.0f;
        s_c1[i] = (vessel && cb == 0) ? 1.0f : 0.0f;
    }
    __syncthreads();

    const int nquads = VOL / 4;                       // 4,194,304 float4 groups
    const int stride = gridDim.x * blockDim.x;

    const i32x4* lab4 = reinterpret_cast<const i32x4*>(labels);
    const f32x4* par4 = reinterpret_cast<const f32x4*>(parenchyma);
    f32x4* vol4 = reinterpret_cast<f32x4*>(out);
    f32x4* c04  = reinterpret_cast<f32x4*>(out + (size_t)VOL);
    f32x4* c14  = reinterpret_cast<f32x4*>(out + 2 * (size_t)VOL);
    f32x4* c24  = reinterpret_cast<f32x4*>(out + 3 * (size_t)VOL);

    for (int q = blockIdx.x * blockDim.x + tid; q < nquads; q += stride) {
        const i32x4 lab = __builtin_nontemporal_load(&lab4[q]);
        const f32x4 par = __builtin_nontemporal_load(&par4[q]);

        f32x4 vol, c0, c1, c2;

        #pragma unroll
        for (int e = 0; e < 4; ++e) {
            const int l = lab[e];
            const float vf = (l > 0) ? 1.0f : 0.0f;
            vol[e] = par[e] * s_scale[l];
            c1[e] = s_c1[l];
            c0[e] = 1.0f - vf;
            c2[e] = vf - c1[e];
        }

        __builtin_nontemporal_store(vol, &vol4[q]);
        __builtin_nontemporal_store(c0, &c04[q]);
        __builtin_nontemporal_store(c1, &c14[q]);
        __builtin_nontemporal_store(c2, &c24[q]);
    }
}

extern "C" void kernel_launch(void* const* d_in, const int* in_sizes, int n_in,
                              void* d_out, int out_size, void* d_ws, size_t ws_size,
                              hipStream_t stream) {
    const int*   labels      = (const int*)d_in[0];
    const float* intensities = (const float*)d_in[1];
    const int*   class_bits  = (const int*)d_in[2];
    const float* parenchyma  = (const float*)d_in[3];
    float* out = (float*)d_out;

    const int blocks = 2048;   // 256 CUs x 8 blocks; grid-stride covers 4.19M quads
    YibeiVessels_74156905333425_kernel<<<blocks, 256, 0, stream>>>(
        labels, intensities, class_bits, parenchyma, out);
}